// Round 11
// baseline (114.203 us; speedup 1.0000x reference)
//
#include <hip/hip_runtime.h>
#include <hip/hip_bf16.h>

typedef __attribute__((ext_vector_type(8))) short short8;
typedef __attribute__((ext_vector_type(4))) short s16x4;
typedef __attribute__((ext_vector_type(4))) float f32x4;
typedef __attribute__((ext_vector_type(16))) float f32x16;

#define N_ATOMS 100000
#define N_EDGES 800000
#define N_TILES (N_EDGES/16)        // 16-edge tiles (fallback kernel)
#define N_TILES32 (N_EDGES/32)      // 25000 tiles of 32 edges (main kernel)
#define N_CHUNKS ((N_ATOMS + 255) / 256)   // 391 scan chunks

// edge_msg v6: ONE wave per 32-edge tile via mfma_f32_32x32x16_bf16.
// 768 blocks (3/CU) * 4 waves = 3072 waves, ~8.1 bodies/wave.
#define MSG_BLOCKS 768
#define MSG_WAVES  (MSG_BLOCKS*4)

// ---- ws layout (bytes) ----
#define WS_MSG     0ULL                      // bf16 msg [N_EDGES][32] = 51,200,000
#define WS_OFFS    51200000ULL               // int offsets [N_ATOMS+1]
#define WS_COUNTS  51600016ULL               // int counts [N_ATOMS]
#define WS_RANK    58400016ULL               // int rank [N_EDGES]
#define WS_PART    61600016ULL               // int partials [512]
#define WS_NEED    61602064ULL

__device__ __forceinline__ short f2bf(float x) {
    __hip_bfloat16 h = __float2bfloat16(x);
    return __builtin_bit_cast(short, h);
}
__device__ __forceinline__ float bf2f(short b) {
    unsigned u = ((unsigned)(unsigned short)b) << 16;
    return __builtin_bit_cast(float, u);
}

// ---------------- CSR build (plain dispatches; R9: grid.sync ~90us/sync, never again) ----------------
__global__ __launch_bounds__(256) void rank_kernel(const int2* __restrict__ pair,
                                                   int* __restrict__ counts,
                                                   int* __restrict__ rank) {
    int e = blockIdx.x * 256 + threadIdx.x;
    if (e < N_EDGES) rank[e] = atomicAdd(&counts[pair[e].x], 1);
}

__global__ __launch_bounds__(256) void scan_part(const int* __restrict__ counts,
                                                 int* __restrict__ partials) {
    const int tid = threadIdx.x;
    const int i = blockIdx.x * 256 + tid;
    int v = (i < N_ATOMS) ? counts[i] : 0;
#pragma unroll
    for (int off = 1; off < 64; off <<= 1) v += __shfl_xor(v, off);
    __shared__ int ws4[4];
    const int lane = tid & 63, wv = tid >> 6;
    if (lane == 0) ws4[wv] = v;
    __syncthreads();
    if (tid == 0) partials[blockIdx.x] = ws4[0] + ws4[1] + ws4[2] + ws4[3];
}

__global__ __launch_bounds__(512) void scan_mid(int* __restrict__ partials) {
    const int tid = threadIdx.x;
    const int lane = tid & 63, wv = tid >> 6;
    int v = (tid < N_CHUNKS) ? partials[tid] : 0;
    int inc = v;
#pragma unroll
    for (int off = 1; off < 64; off <<= 1) {
        int u = __shfl_up(inc, off);
        if (lane >= off) inc += u;
    }
    __shared__ int ws8[8];
    if (lane == 63) ws8[wv] = inc;
    __syncthreads();
    int base = 0;
#pragma unroll
    for (int k = 0; k < 8; ++k) base += (k < wv) ? ws8[k] : 0;
    if (tid < N_CHUNKS) partials[tid] = base + inc - v;   // exclusive
}

__global__ __launch_bounds__(256) void scan_final(const int* __restrict__ counts,
                                                  const int* __restrict__ partials,
                                                  int* __restrict__ offsets) {
    const int tid = threadIdx.x;
    const int i = blockIdx.x * 256 + tid;
    const int lane = tid & 63, wv = tid >> 6;
    int c = (i < N_ATOMS) ? counts[i] : 0;
    int inc = c;
#pragma unroll
    for (int off = 1; off < 64; off <<= 1) {
        int u = __shfl_up(inc, off);
        if (lane >= off) inc += u;
    }
    __shared__ int ws4[4];
    if (lane == 63) ws4[wv] = inc;
    __syncthreads();
    int base = partials[blockIdx.x];
#pragma unroll
    for (int k = 0; k < 4; ++k) base += (k < wv) ? ws4[k] : 0;
    const int off = base + inc - c;                        // exclusive prefix
    if (i < N_ATOMS) offsets[i] = off;
    if (i == N_ATOMS - 1) offsets[N_ATOMS] = off + c;
}

// ---------------- phase A: per-edge messages via 32x32x16 MFMA ----------------
// One wave per 32-edge tile. Lane owns edge el=lane&31, j/K-half hi=lane>>5.
// D_b[i][e] (32x32) = K_b(32x32) x neigh^T(32x32edges), split into 2 MFMAs over j
// (K=16 each), chained via C-in. msg[e][i] = sum_b bond[e][b]*D_b + bias-channel
// (bias = macc initializer via C-in). C/D: col=el, row=(reg&3)+8*(reg>>2)+4*hi.
// Pipeline: pair/rank dist-2; bond+offsets+atom-gather dist-1 (~1 body cover);
// persistent bfrag kept in bf16 (8 regs); h=1 A-frags re-read from LDS (anti-LICM).
__global__ __launch_bounds__(256, 3)
void edge_msg_kernel(const float* __restrict__ atom,
                     const float* __restrict__ bond,
                     const float* __restrict__ kern,
                     const float* __restrict__ bias,
                     const int2*  __restrict__ pair,
                     const int*   __restrict__ rank,
                     const int*   __restrict__ offsets,
                     short*       __restrict__ msg)
{
    __shared__ __align__(16) short klds[17*2*512];   // 34816 B: [b][h][lane][8]
    __shared__ __align__(16) float blds[4*32*20];    // 10240 B bond bounce (80B/edge)

    const int tid = threadIdx.x;
    for (int x = tid; x < 17*2*512; x += 256) {
        const int t = x & 7;
        const int l = (x >> 3) & 63;
        const int h = (x >> 9) & 1;
        const int b = x >> 10;
        const int i = l & 31;                        // A row (output feature)
        const int j = h*16 + ((l >> 5) << 3) + t;    // A k (neighbor feature)
        const float v = (b < 16) ? kern[b*1024 + i*32 + j] : bias[i*32 + j];
        klds[x] = f2bf(v);
    }
    __syncthreads();

    const int wave = tid >> 6;
    const int lane = tid & 63;
    const int el   = lane & 31;   // this lane's edge (B col, D col)
    const int hi   = lane >> 5;   // K-half / row-offset group
    const int pid  = blockIdx.x * 4 + wave;          // 0..3071

    short8 afr[17];                                  // h=0 frags (incl. bias)
#pragma unroll
    for (int b = 0; b < 17; ++b)
        afr[b] = *(const short8*)&klds[(b*2 + 0)*512 + lane*8];

    // bond staging: write map lane l -> edge l>>1, 32B half l&1; read per-edge
    float* bw = &blds[wave*640 + (lane >> 1)*20 + (lane & 1)*8];
    const float* brd = &blds[wave*640 + el*20];

    const int last = N_TILES32 - 1;

    // ---- prologue: tile t0 bond->LDS, t0 state, t1 pair/rank ----
    const int t1p = min(pid + MSG_WAVES, last);
    int2 p0 = pair[pid*32 + el];
    int  r0 = rank[pid*32 + el];
    int2 p1 = pair[t1p*32 + el];
    int  r1 = rank[t1p*32 + el];
    {
        const float* bsrc = bond + ((long long)pid*32 + (lane >> 1))*16 + (lane & 1)*8;
        const f32x4 bva = *(const f32x4*)bsrc;
        const f32x4 bvb = *(const f32x4*)(bsrc + 4);
        *(f32x4*)bw = bva;
        *(f32x4*)(bw + 4) = bvb;
    }
    int o0 = offsets[p0.x];
    short8 b0f, b1f;
    {
        const float* ap = atom + p0.y*32 + hi*8;
        const f32x4 na0 = *(const f32x4*)ap;
        const f32x4 na1 = *(const f32x4*)(ap + 4);
        const f32x4 nb0 = *(const f32x4*)(ap + 16);
        const f32x4 nb1 = *(const f32x4*)(ap + 20);
        b0f[0]=f2bf(na0[0]); b0f[1]=f2bf(na0[1]); b0f[2]=f2bf(na0[2]); b0f[3]=f2bf(na0[3]);
        b0f[4]=f2bf(na1[0]); b0f[5]=f2bf(na1[1]); b0f[6]=f2bf(na1[2]); b0f[7]=f2bf(na1[3]);
        b1f[0]=f2bf(nb0[0]); b1f[1]=f2bf(nb0[1]); b1f[2]=f2bf(nb0[2]); b1f[3]=f2bf(nb0[3]);
        b1f[4]=f2bf(nb1[0]); b1f[5]=f2bf(nb1[1]); b1f[6]=f2bf(nb1[2]); b1f[7]=f2bf(nb1[3]);
    }

    for (int t = pid; t < N_TILES32; t += MSG_WAVES) {
        // opaque zero: pins per-body klds frag reads inside the loop (anti-LICM)
        int koff = 0;
        asm volatile("" : "+v"(koff));

        // dist-2: pair/rank for t+2
        const int t2 = min(t + 2*MSG_WAVES, last);
        const int2 p2 = pair[t2*32 + el];
        const int  r2 = rank[t2*32 + el];

        // dist-1: bond for t+1 (LDS-staged at body end), offsets+atom gather for t+1
        const int t1 = min(t + MSG_WAVES, last);
        const float* bsrc = bond + ((long long)t1*32 + (lane >> 1))*16 + (lane & 1)*8;
        const f32x4 bva = *(const f32x4*)bsrc;
        const f32x4 bvb = *(const f32x4*)(bsrc + 4);
        const int   o1  = offsets[p1.x];
        const float* ap = atom + p1.y*32 + hi*8;
        const f32x4 na0 = *(const f32x4*)ap;
        const f32x4 na1 = *(const f32x4*)(ap + 4);
        const f32x4 nb0 = *(const f32x4*)(ap + 16);
        const f32x4 nb1 = *(const f32x4*)(ap + 20);

        // ---- MFMA block for tile t (bfrag cvt'd last body) ----
        const f32x16 zz = {0.f,0.f,0.f,0.f,0.f,0.f,0.f,0.f,
                           0.f,0.f,0.f,0.f,0.f,0.f,0.f,0.f};
        // bias channel initializes macc (unit coefficient, C-in chaining)
        const short8 ab1f = *(const short8*)&klds[(16*2 + 1)*512 + lane*8 + koff];
        f32x16 macc = __builtin_amdgcn_mfma_f32_32x32x16_bf16(afr[16], b0f, zz, 0, 0, 0);
        macc = __builtin_amdgcn_mfma_f32_32x32x16_bf16(ab1f, b1f, macc, 0, 0, 0);
#pragma unroll
        for (int g = 0; g < 4; ++g) {
            const f32x4 q = *(const f32x4*)(brd + g*4);   // 4 bond coeffs (lane-local edge)
#pragma unroll
            for (int c = 0; c < 4; ++c) {
                const int b = g*4 + c;
                const short8 a1 = *(const short8*)&klds[(b*2 + 1)*512 + lane*8 + koff];
                f32x16 d = __builtin_amdgcn_mfma_f32_32x32x16_bf16(afr[b], b0f, zz, 0, 0, 0);
                d = __builtin_amdgcn_mfma_f32_32x32x16_bf16(a1, b1f, d, 0, 0, 0);
#pragma unroll
                for (int r = 0; r < 16; ++r)
                    macc[r] = fmaf(q[c], d[r], macc[r]);
            }
        }

        // stage bond t+1 (single buffer: brd reads above already issued, DS in-order)
        *(f32x4*)bw = bva;
        *(f32x4*)(bw + 4) = bvb;

        // cvt next bfrag (gathers issued this body top: ~full MFMA block of cover)
        b0f[0]=f2bf(na0[0]); b0f[1]=f2bf(na0[1]); b0f[2]=f2bf(na0[2]); b0f[3]=f2bf(na0[3]);
        b0f[4]=f2bf(na1[0]); b0f[5]=f2bf(na1[1]); b0f[6]=f2bf(na1[2]); b0f[7]=f2bf(na1[3]);
        b1f[0]=f2bf(nb0[0]); b1f[1]=f2bf(nb0[1]); b1f[2]=f2bf(nb0[2]); b1f[3]=f2bf(nb0[3]);
        b1f[4]=f2bf(nb1[0]); b1f[5]=f2bf(nb1[1]); b1f[6]=f2bf(nb1[2]); b1f[7]=f2bf(nb1[3]);

        // store tile t: lane owns edge el; rows (reg&3)+8*(reg>>2)+4*hi
        const int sl = o0 + r0;
#pragma unroll
        for (int g = 0; g < 4; ++g) {
            s16x4 mv;
            mv[0]=f2bf(macc[4*g+0]); mv[1]=f2bf(macc[4*g+1]);
            mv[2]=f2bf(macc[4*g+2]); mv[3]=f2bf(macc[4*g+3]);
            *(s16x4*)&msg[sl*32 + g*8 + hi*4] = mv;
        }

        // rotate pipeline state
        p0 = p1; r0 = r1; o0 = o1; p1 = p2; r1 = r2;
    }
}

// ---------------- phase B: per-atom gather-sum (atomic-free, 2x unroll) ----------------
__global__ __launch_bounds__(256) void gather_kernel(const short* __restrict__ msg,
                                                     const int* __restrict__ offsets,
                                                     float* __restrict__ out) {
    const int tid = threadIdx.x;
    const int a = blockIdx.x * 32 + (tid >> 3);
    const int sub = (tid & 7) * 4;
    if (a >= N_ATOMS) return;
    const int b0 = offsets[a], b1 = offsets[a + 1];
    f32x4 acc0 = {0.f, 0.f, 0.f, 0.f};
    f32x4 acc1 = {0.f, 0.f, 0.f, 0.f};
    int k = b0;
    for (; k + 1 < b1; k += 2) {
        s16x4 mv0 = *(const s16x4*)&msg[k*32 + sub];
        s16x4 mv1 = *(const s16x4*)&msg[(k+1)*32 + sub];
        acc0[0] += bf2f(mv0[0]); acc0[1] += bf2f(mv0[1]);
        acc0[2] += bf2f(mv0[2]); acc0[3] += bf2f(mv0[3]);
        acc1[0] += bf2f(mv1[0]); acc1[1] += bf2f(mv1[1]);
        acc1[2] += bf2f(mv1[2]); acc1[3] += bf2f(mv1[3]);
    }
    if (k < b1) {
        s16x4 mv0 = *(const s16x4*)&msg[k*32 + sub];
        acc0[0] += bf2f(mv0[0]); acc0[1] += bf2f(mv0[1]);
        acc0[2] += bf2f(mv0[2]); acc0[3] += bf2f(mv0[3]);
    }
    acc0[0] += acc1[0]; acc0[1] += acc1[1]; acc0[2] += acc1[2]; acc0[3] += acc1[3];
    *(f32x4*)&out[a*32 + sub] = acc0;
}

// ---------------- fallback (R1 atomic version, known-passing) ----------------
__global__ __launch_bounds__(256) void zero_out(f32x4* __restrict__ out) {
    int i = blockIdx.x * 256 + threadIdx.x;
    f32x4 z = {0.f, 0.f, 0.f, 0.f};
    out[i] = z;
}

__global__ __launch_bounds__(256, 4)
void edge_kernel_atomic(const float* __restrict__ atom, const float* __restrict__ bond,
                        const int2* __restrict__ pair, const float* __restrict__ kern,
                        const float* __restrict__ bias, float* __restrict__ out)
{
    __shared__ __align__(16) short alds[17*2*512];
    const int tid = threadIdx.x;
    for (int x = tid; x < 17*2*512; x += 256) {
        const int t = x & 7;
        const int l = (x >> 3) & 63;
        const int m = (x >> 9) & 1;
        const int b = x >> 10;
        const int i = m*16 + (l & 15);
        const int j = ((l >> 4) << 3) + t;
        const float v = (b < 16) ? kern[b*1024 + i*32 + j] : bias[i*32 + j];
        alds[x] = f2bf(v);
    }
    __syncthreads();
    const int wave = tid >> 6, lane = tid & 63;
    const int er = lane & 15, jg = lane >> 4;
    const int wid = blockIdx.x * 4 + wave;
    const int m = wid & 1, pid = wid >> 1;
    short8 afr[17];
#pragma unroll
    for (int b = 0; b < 17; ++b)
        afr[b] = *(const short8*)&alds[(b*2 + m)*512 + lane*8];
    const int ibase = m*16 + jg*4;
    for (int tile = pid; tile < N_TILES; tile += 2048) {
        const int e = tile*16 + er;
        const int2 p = pair[e];
        const f32x4* arow = (const f32x4*)(atom + p.y * 32);
        const f32x4 n0 = arow[jg*2];
        const f32x4 n1 = arow[jg*2 + 1];
        short8 bfrag;
        bfrag[0] = f2bf(n0[0]); bfrag[1] = f2bf(n0[1]);
        bfrag[2] = f2bf(n0[2]); bfrag[3] = f2bf(n0[3]);
        bfrag[4] = f2bf(n1[0]); bfrag[5] = f2bf(n1[1]);
        bfrag[6] = f2bf(n1[2]); bfrag[7] = f2bf(n1[3]);
        const f32x4* brow = (const f32x4*)(bond + e * 16);
        const f32x4 q0 = brow[0], q1 = brow[1], q2 = brow[2], q3 = brow[3];
        float bb[17];
        bb[0]=q0[0];  bb[1]=q0[1];  bb[2]=q0[2];  bb[3]=q0[3];
        bb[4]=q1[0];  bb[5]=q1[1];  bb[6]=q1[2];  bb[7]=q1[3];
        bb[8]=q2[0];  bb[9]=q2[1];  bb[10]=q2[2]; bb[11]=q2[3];
        bb[12]=q3[0]; bb[13]=q3[1]; bb[14]=q3[2]; bb[15]=q3[3];
        bb[16]=1.0f;
        f32x4 macc = {0.f,0.f,0.f,0.f};
#pragma unroll
        for (int b = 0; b < 17; ++b) {
            f32x4 z = {0.f,0.f,0.f,0.f};
            f32x4 d = __builtin_amdgcn_mfma_f32_16x16x32_bf16(afr[b], bfrag, z, 0, 0, 0);
            macc[0] = fmaf(bb[b], d[0], macc[0]);
            macc[1] = fmaf(bb[b], d[1], macc[1]);
            macc[2] = fmaf(bb[b], d[2], macc[2]);
            macc[3] = fmaf(bb[b], d[3], macc[3]);
        }
        float* obase = out + p.x * 32 + ibase;
        atomicAdd(obase + 0, macc[0]);
        atomicAdd(obase + 1, macc[1]);
        atomicAdd(obase + 2, macc[2]);
        atomicAdd(obase + 3, macc[3]);
    }
}

extern "C" void kernel_launch(void* const* d_in, const int* in_sizes, int n_in,
                              void* d_out, int out_size, void* d_ws, size_t ws_size,
                              hipStream_t stream)
{
    (void)in_sizes; (void)n_in; (void)out_size;
    const float* atom = (const float*)d_in[0];
    const float* bond = (const float*)d_in[1];
    const int2*  pair = (const int2*)d_in[2];
    const float* kern = (const float*)d_in[3];
    const float* bias = (const float*)d_in[4];
    float* out = (float*)d_out;

    if (ws_size < WS_NEED) {
        zero_out<<<dim3(N_ATOMS*32/4/256), dim3(256), 0, stream>>>((f32x4*)out);
        edge_kernel_atomic<<<dim3(1024), dim3(256), 0, stream>>>(atom, bond, pair, kern, bias, out);
        return;
    }

    char* ws = (char*)d_ws;
    short* msg    = (short*)(ws + WS_MSG);
    int* offsets  = (int*)(ws + WS_OFFS);
    int* counts   = (int*)(ws + WS_COUNTS);
    int* rank     = (int*)(ws + WS_RANK);
    int* partials = (int*)(ws + WS_PART);

    const int eb = (N_EDGES + 255) / 256;          // 3125
    hipMemsetAsync(counts, 0, N_ATOMS * sizeof(int), stream);
    rank_kernel<<<dim3(eb), dim3(256), 0, stream>>>(pair, counts, rank);
    scan_part<<<dim3(N_CHUNKS), dim3(256), 0, stream>>>(counts, partials);
    scan_mid<<<dim3(1), dim3(512), 0, stream>>>(partials);
    scan_final<<<dim3(N_CHUNKS), dim3(256), 0, stream>>>(counts, partials, offsets);
    edge_msg_kernel<<<dim3(MSG_BLOCKS), dim3(256), 0, stream>>>(atom, bond, kern, bias, pair, rank, offsets, msg);
    gather_kernel<<<dim3((N_ATOMS + 31)/32), dim3(256), 0, stream>>>(msg, offsets, out);
}